// Round 4
// baseline (689.149 us; speedup 1.0000x reference)
//
#include <hip/hip_runtime.h>
#include <stdint.h>

// coAttention live compute after DCE (v3 — resubmission of the chunk-ring
// counted-vmcnt design; R2/R3 container failures were infra-side, kernel
// re-audited for barrier-divergence / vmcnt / WAR / OOB hazards):
//   q[b]   = Wp @ Q[b] + bp
//   T[b]   = [W3|W4] @ [M[b]; q[b]] + b3
//   out[b] = relu(T[b]) * q[b]
// bf16 MFMA 16x16x32, fp32 accum. B=32, D=1024.
// GEMMs: 256x256 tile, BK=64, 8 waves (2Mx4N), double-buffered 128KiB LDS,
// T2 XOR-swizzle, chunk-ring staging with COUNTED vmcnt(4) (T3+T4: one chunk
// staged per phase at region-death, never drain to 0 mid-loop), T5 setprio,
// T1 bijective XCD swizzle.

#define D_ 1024

typedef __attribute__((ext_vector_type(8))) short short8;
typedef __attribute__((ext_vector_type(4))) float floatx4;
typedef __attribute__((ext_vector_type(4))) unsigned short us4;

#define VMCNT0() asm volatile("s_waitcnt vmcnt(0)" ::: "memory")
#define VMCNT4() asm volatile("s_waitcnt vmcnt(4)" ::: "memory")
#define LGKM0()  asm volatile("s_waitcnt lgkmcnt(0)" ::: "memory")

__device__ __forceinline__ unsigned short f2bf(float f) {
  union { float f; unsigned int u; } v; v.f = f;
  unsigned int u = v.u;
  unsigned int r = (u + 0x7FFFu + ((u >> 16) & 1u)) >> 16;  // RNE
  return (unsigned short)r;
}

__device__ __forceinline__ float bf2f(unsigned short h) {
  union { unsigned int u; float f; } v; v.u = ((unsigned int)h) << 16;
  return v.f;
}

// async global->LDS, 16B/lane; LDS dest is wave-uniform base + lane*16
__device__ __forceinline__ void async_load16(const void* g, void* l) {
  __builtin_amdgcn_global_load_lds(
      (const __attribute__((address_space(1))) unsigned int*)g,
      (__attribute__((address_space(3))) unsigned int*)l, 16, 0, 0);
}

// ---------------- Pass 0a: transpose + fp32->bf16, both Q and M in one launch
__global__ __launch_bounds__(256) void transpose_cvt2(
    const float* __restrict__ in0, unsigned short* __restrict__ out0,
    const float* __restrict__ in1, unsigned short* __restrict__ out1) {
  __shared__ float tile[64][65];
  const int zz = blockIdx.z;
  const float* in = (zz < 32) ? in0 : in1;
  unsigned short* out = (zz < 32) ? out0 : out1;
  const int b = zz & 31;
  const long base = ((long)b) << 20;
  const int r0 = blockIdx.y * 64, c0 = blockIdx.x * 64;
  const int t = threadIdx.x;
  const int tr = t >> 4, tc4 = (t & 15) * 4;
#pragma unroll
  for (int p = 0; p < 4; ++p) {
    const int row = p * 16 + tr;
    const float4 v = *(const float4*)&in[base + (long)(r0 + row) * D_ + c0 + tc4];
    tile[row][tc4 + 0] = v.x; tile[row][tc4 + 1] = v.y;
    tile[row][tc4 + 2] = v.z; tile[row][tc4 + 3] = v.w;
  }
  __syncthreads();
#pragma unroll
  for (int p = 0; p < 4; ++p) {
    const int c = p * 16 + tr;
    us4 pk;
    pk.x = f2bf(tile[tc4 + 0][c]);
    pk.y = f2bf(tile[tc4 + 1][c]);
    pk.z = f2bf(tile[tc4 + 2][c]);
    pk.w = f2bf(tile[tc4 + 3][c]);
    *(us4*)&out[base + (long)(c0 + c) * D_ + r0 + tc4] = pk;
  }
}

// ---------------- Pass 0b: convert weights; A2 = [W3 | W4] 1024x2048
__global__ __launch_bounds__(256) void convert_weights(
    const float* __restrict__ Wp, const float* __restrict__ W3,
    const float* __restrict__ W4, unsigned short* __restrict__ Wpb,
    unsigned short* __restrict__ A2) {
  const int i = blockIdx.x * 256 + threadIdx.x;
  const long e = (long)i * 4;
  const int row = (int)(e >> 10);
  const int col = (int)(e & 1023);
  const float4 a = ((const float4*)Wp)[i];
  us4 pa; pa.x = f2bf(a.x); pa.y = f2bf(a.y); pa.z = f2bf(a.z); pa.w = f2bf(a.w);
  ((us4*)Wpb)[i] = pa;
  const float4 w3 = ((const float4*)W3)[i];
  us4 p3; p3.x = f2bf(w3.x); p3.y = f2bf(w3.y); p3.z = f2bf(w3.z); p3.w = f2bf(w3.w);
  *(us4*)&A2[(long)row * 2048 + col] = p3;
  const float4 w4 = ((const float4*)W4)[i];
  us4 p4; p4.x = f2bf(w4.x); p4.y = f2bf(w4.y); p4.z = f2bf(w4.z); p4.w = f2bf(w4.w);
  *(us4*)&A2[(long)row * 2048 + 1024 + col] = p4;
}

// ---------------- 256x256 counted-vmcnt GEMM (both passes)
// A: [1024][LDA] bf16 row-major (k-contiguous). B^T rows: [1024][1024] k-major.
// gemm1 (!IS_G2): B^T = Qt[b]; out = qt (bf16 k-major) with +bias.
// gemm2 ( IS_G2): B^T rows kt<16 from Mt[b], kt>=16 from qt[b];
//                 out fp32 = relu(acc+bias) * q (read from qt k-major).
//
// Chunk ring (per wave, 2 global_load_lds per chunk):
//   tile t ph0: stage A-half0(t+1) -> buf^1   [A of buf^1 died at t-1.ph2]
//   tile t ph1: stage A-half1(t+1) -> buf^1
//   tile t ph2: stage B-half0(t+2) -> buf     [B of buf died at t.ph1]
//   tile t ph3: stage B-half1(t+2) -> buf
//   boundary:   vmcnt(4)  -> A(t+1)+B(t+1) landed; B(t+2) stays in flight
template <int NT, int LDA, bool IS_G2>
__global__ __launch_bounds__(512, 2) void gemm8p(
    const unsigned short* __restrict__ A,
    const unsigned short* __restrict__ B1,
    const unsigned short* __restrict__ B2,
    const float* __restrict__ bias,
    void* __restrict__ outp) {
  __shared__ __align__(16) unsigned short As[2][256 * 64];
  __shared__ __align__(16) unsigned short Bs[2][256 * 64];

  const int lane = threadIdx.x & 63;
  const int w = threadIdx.x >> 6;
  const int wm = (w >> 2) * 128;   // wave M offset: rows wm..wm+127 (one A-half)
  const int wn = (w & 3) * 64;     // wave N offset: rows wn..wn+63 (one B-half)
  const int l15 = lane & 15;
  const int quad = lane >> 4;

  // T1: bijective chunked XCD swizzle (nwg=512, 512%8==0)
  const int bid = blockIdx.x;
  const int swz = (bid & 7) * 64 + (bid >> 3);
  const int b = swz >> 4;
  const int m0 = ((swz >> 2) & 3) * 256;
  const int n0 = (swz & 3) * 256;
  const long bb = ((long)b) << 20;

  // staging: linear LDS dest; global source pre-swizzled so the read-side
  // XOR (byte ^= (row&7)<<4) sees the right data (rule 21)
  const int sr = lane >> 3;
  const int sc = ((lane & 7) ^ sr) * 8;

  const unsigned short* Ag = A + (long)(m0 + w * 16 + sr) * LDA + sc;
  const unsigned short* Bg1 = B1 + bb + (long)(n0 + w * 16 + sr) * D_ + sc;
  const unsigned short* Bg2 =
      B2 ? (B2 + bb + (long)(n0 + w * 16 + sr) * D_ + sc) : (const unsigned short*)0;

  const int kx0 = (quad * 16) ^ ((lane & 7) << 4);
  const int kx1 = (64 + quad * 16) ^ ((lane & 7) << 4);

  floatx4 acc[8][4] = {};

  // one chunk = half an operand tile (128 rows x 64 cols bf16) = 2 loads/wave
  auto stageAh = [&](int buf, int kt, int h) {
#pragma unroll
    for (int j = 0; j < 2; ++j)
      async_load16(Ag + (long)(h * 128 + j * 8) * LDA + (long)kt * 64,
                   &As[buf][(h * 128 + w * 16 + j * 8) * 64]);
  };
  auto stageBh = [&](int buf, int kt, int h) {
    const unsigned short* bs;
    if constexpr (IS_G2) {
      bs = (kt < 16) ? (Bg1 + (long)kt * 64) : (Bg2 + (long)(kt - 16) * 64);
    } else {
      bs = Bg1 + (long)kt * 64;
    }
#pragma unroll
    for (int j = 0; j < 2; ++j)
      async_load16(bs + (long)(h * 128 + j * 8) * D_,
                   &Bs[buf][(h * 128 + w * 16 + j * 8) * 64]);
  };

  auto ldA = [&](int buf, int fi, int kx) -> short8 {
    return *(const short8*)((const char*)&As[buf][0] +
                            (long)((wm + fi * 16 + l15) * 128 + kx));
  };
  auto ldB = [&](int buf, int fi, int kx) -> short8 {
    return *(const short8*)((const char*)&Bs[buf][0] +
                            (long)((wn + fi * 16 + l15) * 128 + kx));
  };

  // prologue: A(0), B(0) awaited; B(1) left in flight
  stageAh(0, 0, 0); stageAh(0, 0, 1);
  stageBh(0, 0, 0); stageBh(0, 0, 1);
  stageBh(1, 1, 0); stageBh(1, 1, 1);
  VMCNT4();
  __builtin_amdgcn_s_barrier();

  short8 a[4][2], bq[4][2];

  auto tile = [&](int t, int buf) {
    // ---- ph0: (mq0,nq0); read a[0..3]+b[0,1]; stage A-half0(t+1)
#pragma unroll
    for (int r = 0; r < 4; ++r) { a[r][0] = ldA(buf, r, kx0); a[r][1] = ldA(buf, r, kx1); }
#pragma unroll
    for (int c = 0; c < 2; ++c) { bq[c][0] = ldB(buf, c, kx0); bq[c][1] = ldB(buf, c, kx1); }
    if (t + 1 < NT) stageAh(buf ^ 1, t + 1, 0);
    __builtin_amdgcn_s_barrier();
    LGKM0();
    __builtin_amdgcn_sched_barrier(0);
    __builtin_amdgcn_s_setprio(1);
#pragma unroll
    for (int r = 0; r < 4; ++r)
#pragma unroll
      for (int c = 0; c < 2; ++c)
#pragma unroll
        for (int ks = 0; ks < 2; ++ks)
          acc[r][c] = __builtin_amdgcn_mfma_f32_16x16x32_bf16(
              a[r][ks], bq[c][ks], acc[r][c], 0, 0, 0);
    __builtin_amdgcn_s_setprio(0);
    __builtin_amdgcn_s_barrier();

    // ---- ph1: (mq0,nq1); read b[2,3]; stage A-half1(t+1)
#pragma unroll
    for (int c = 0; c < 2; ++c) { bq[2 + c][0] = ldB(buf, 2 + c, kx0); bq[2 + c][1] = ldB(buf, 2 + c, kx1); }
    if (t + 1 < NT) stageAh(buf ^ 1, t + 1, 1);
    __builtin_amdgcn_s_barrier();
    LGKM0();
    __builtin_amdgcn_sched_barrier(0);
    __builtin_amdgcn_s_setprio(1);
#pragma unroll
    for (int r = 0; r < 4; ++r)
#pragma unroll
      for (int c = 0; c < 2; ++c)
#pragma unroll
        for (int ks = 0; ks < 2; ++ks)
          acc[r][2 + c] = __builtin_amdgcn_mfma_f32_16x16x32_bf16(
              a[r][ks], bq[2 + c][ks], acc[r][2 + c], 0, 0, 0);
    __builtin_amdgcn_s_setprio(0);
    __builtin_amdgcn_s_barrier();

    // ---- ph2: (mq1,nq1); read a[4..7]; stage B-half0(t+2) into buf (B dead)
#pragma unroll
    for (int r = 0; r < 4; ++r) { a[r][0] = ldA(buf, 4 + r, kx0); a[r][1] = ldA(buf, 4 + r, kx1); }
    if (t + 2 < NT) stageBh(buf, t + 2, 0);
    __builtin_amdgcn_s_barrier();
    LGKM0();
    __builtin_amdgcn_sched_barrier(0);
    __builtin_amdgcn_s_setprio(1);
#pragma unroll
    for (int r = 0; r < 4; ++r)
#pragma unroll
      for (int c = 0; c < 2; ++c)
#pragma unroll
        for (int ks = 0; ks < 2; ++ks)
          acc[4 + r][2 + c] = __builtin_amdgcn_mfma_f32_16x16x32_bf16(
              a[r][ks], bq[2 + c][ks], acc[4 + r][2 + c], 0, 0, 0);
    __builtin_amdgcn_s_setprio(0);
    __builtin_amdgcn_s_barrier();

    // ---- ph3: (mq1,nq0); no LDS reads; stage B-half1(t+2); counted boundary
    if (t + 2 < NT) stageBh(buf, t + 2, 1);
    __builtin_amdgcn_s_barrier();
    __builtin_amdgcn_s_setprio(1);
#pragma unroll
    for (int r = 0; r < 4; ++r)
#pragma unroll
      for (int c = 0; c < 2; ++c)
#pragma unroll
        for (int ks = 0; ks < 2; ++ks)
          acc[4 + r][c] = __builtin_amdgcn_mfma_f32_16x16x32_bf16(
              a[r][ks], bq[c][ks], acc[4 + r][c], 0, 0, 0);
    __builtin_amdgcn_s_setprio(0);
    if (t < NT - 2) { VMCNT4(); } else { VMCNT0(); }
    __builtin_amdgcn_s_barrier();
  };

#pragma unroll 1
  for (int tt = 0; tt < NT; tt += 2) {
    tile(tt, 0);
    tile(tt + 1, 1);
  }

  // ---- epilogue. C/D map: col = n-part + (lane&15), row = m-part + quad*4 + reg
  if constexpr (!IS_G2) {
    unsigned short* qt = (unsigned short*)outp;
#pragma unroll
    for (int c = 0; c < 4; ++c) {
      const int col = n0 + wn + c * 16 + l15;
      const float bv = bias[col];
#pragma unroll
      for (int r = 0; r < 8; ++r) {
        const int row = m0 + wm + r * 16 + quad * 4;
        const floatx4 v = acc[r][c];
        us4 pk;
        pk.x = f2bf(v.x + bv); pk.y = f2bf(v.y + bv);
        pk.z = f2bf(v.z + bv); pk.w = f2bf(v.w + bv);
        *(us4*)&qt[bb + (long)col * D_ + row] = pk;
      }
    }
  } else {
    float* outv = (float*)outp;
#pragma unroll
    for (int c = 0; c < 4; ++c) {
      const int col = n0 + wn + c * 16 + l15;
      const float bv = bias[col];
#pragma unroll
      for (int r = 0; r < 8; ++r) {
        const int row = m0 + wm + r * 16 + quad * 4;
        const floatx4 v = acc[r][c];
        const us4 qv = *(const us4*)&B2[bb + (long)col * D_ + row];
        outv[bb + (long)(row + 0) * D_ + col] = fmaxf(v.x + bv, 0.0f) * bf2f(qv.x);
        outv[bb + (long)(row + 1) * D_ + col] = fmaxf(v.y + bv, 0.0f) * bf2f(qv.y);
        outv[bb + (long)(row + 2) * D_ + col] = fmaxf(v.z + bv, 0.0f) * bf2f(qv.z);
        outv[bb + (long)(row + 3) * D_ + col] = fmaxf(v.w + bv, 0.0f) * bf2f(qv.w);
      }
    }
  }
}

extern "C" void kernel_launch(void* const* d_in, const int* in_sizes, int n_in,
                              void* d_out, int out_size, void* d_ws, size_t ws_size,
                              hipStream_t stream) {
  const float* Q  = (const float*)d_in[1];
  const float* M  = (const float*)d_in[2];
  const float* Wp = (const float*)d_in[4];
  const float* bp = (const float*)d_in[5];
  const float* W3 = (const float*)d_in[6];
  const float* W4 = (const float*)d_in[7];
  const float* b3 = (const float*)d_in[8];
  float* out = (float*)d_out;

  char* ws = (char*)d_ws;
  unsigned short* qt  = (unsigned short*)(ws);                 // 64 MiB: q^T bf16
  unsigned short* Qt  = (unsigned short*)(ws + (64l  << 20));  // 64 MiB: Q^T bf16
  unsigned short* Mt  = (unsigned short*)(ws + (128l << 20));  // 64 MiB: M^T bf16
  unsigned short* Wpb = (unsigned short*)(ws + (192l << 20));  // 2 MiB
  unsigned short* A2  = (unsigned short*)(ws + (194l << 20));  // 4 MiB: [W3|W4]

  dim3 tgrid(16, 16, 64);
  transpose_cvt2<<<tgrid, 256, 0, stream>>>(Q, Qt, M, Mt);
  convert_weights<<<1024, 256, 0, stream>>>(Wp, W3, W4, Wpb, A2);

  // gemm1: q^T = (Wp @ Q[b] + bp)^T   -> qt
  gemm8p<16, 1024, false><<<dim3(512), dim3(512), 0, stream>>>(
      Wpb, Qt, (const unsigned short*)nullptr, bp, qt);
  // gemm2: out = relu([W3|W4] @ [M;q] + b3) * q
  gemm8p<32, 2048, true><<<dim3(512), dim3(512), 0, stream>>>(
      A2, Mt, qt, b3, out);
}

// Round 5
// 674.229 us; speedup vs baseline: 1.0221x; 1.0221x over previous
//
#include <hip/hip_runtime.h>
#include <stdint.h>

// coAttention live compute after DCE (v4 — phase-pipelined LDS reads):
//   q[b]   = Wp @ Q[b] + bp
//   T[b]   = [W3|W4] @ [M[b]; q[b]] + b3
//   out[b] = relu(T[b]) * q[b]
// bf16 MFMA 16x16x32, fp32 accum. B=32, D=1024.
// GEMMs: 256x256 tile, BK=64, 8 waves (2Mx4N), double-buffered 128KiB LDS,
// T2 XOR-swizzle. NEW: every ds_read batch issued ONE PHASE AHEAD inside the
// previous MFMA window; lgkmcnt(0) waits are exact-zero on 1-phase-old
// batches; ONE barrier per phase (4/tile); stages concentrated at ph3 with a
// single exact vmcnt(0) at ph1 (2-phase lead). Quadrant order alternates by
// tile parity so read-aheads always target dead registers.

#define D_ 1024

typedef __attribute__((ext_vector_type(8))) short short8;
typedef __attribute__((ext_vector_type(4))) float floatx4;
typedef __attribute__((ext_vector_type(4))) unsigned short us4;

#define VMCNT0() asm volatile("s_waitcnt vmcnt(0)" ::: "memory")
#define VMCNT8() asm volatile("s_waitcnt vmcnt(8)" ::: "memory")
#define LGKM0()  asm volatile("s_waitcnt lgkmcnt(0)" ::: "memory")
#define SCHED0() __builtin_amdgcn_sched_barrier(0)
#define BAR()    __builtin_amdgcn_s_barrier()

// MFMA quadrant: 4 M-frags x 2 N-frags x 2 K-slices = 16 MFMA. R0/C0 literal.
#define MQ(ASET, BSET, R0, C0)                                               \
  do {                                                                       \
    __builtin_amdgcn_s_setprio(1);                                           \
    _Pragma("unroll") for (int r_ = 0; r_ < 4; ++r_)                         \
        _Pragma("unroll") for (int c_ = 0; c_ < 2; ++c_)                     \
            _Pragma("unroll") for (int k_ = 0; k_ < 2; ++k_)                 \
                acc[(R0) + r_][(C0) + c_] =                                  \
                    __builtin_amdgcn_mfma_f32_16x16x32_bf16(                 \
                        ASET[r_][k_], BSET[c_][k_],                          \
                        acc[(R0) + r_][(C0) + c_], 0, 0, 0);                 \
    __builtin_amdgcn_s_setprio(0);                                           \
  } while (0)

__device__ __forceinline__ unsigned short f2bf(float f) {
  union { float f; unsigned int u; } v; v.f = f;
  unsigned int u = v.u;
  unsigned int r = (u + 0x7FFFu + ((u >> 16) & 1u)) >> 16;  // RNE
  return (unsigned short)r;
}

__device__ __forceinline__ float bf2f(unsigned short h) {
  union { unsigned int u; float f; } v; v.u = ((unsigned int)h) << 16;
  return v.f;
}

// async global->LDS, 16B/lane; LDS dest is wave-uniform base + lane*16
__device__ __forceinline__ void async_load16(const void* g, void* l) {
  __builtin_amdgcn_global_load_lds(
      (const __attribute__((address_space(1))) unsigned int*)g,
      (__attribute__((address_space(3))) unsigned int*)l, 16, 0, 0);
}

// ---------------- Pass 0a: transpose + fp32->bf16, both Q and M in one launch
__global__ __launch_bounds__(256) void transpose_cvt2(
    const float* __restrict__ in0, unsigned short* __restrict__ out0,
    const float* __restrict__ in1, unsigned short* __restrict__ out1) {
  __shared__ float tile[64][65];
  const int zz = blockIdx.z;
  const float* in = (zz < 32) ? in0 : in1;
  unsigned short* out = (zz < 32) ? out0 : out1;
  const int b = zz & 31;
  const long base = ((long)b) << 20;
  const int r0 = blockIdx.y * 64, c0 = blockIdx.x * 64;
  const int t = threadIdx.x;
  const int tr = t >> 4, tc4 = (t & 15) * 4;
#pragma unroll
  for (int p = 0; p < 4; ++p) {
    const int row = p * 16 + tr;
    const float4 v = *(const float4*)&in[base + (long)(r0 + row) * D_ + c0 + tc4];
    tile[row][tc4 + 0] = v.x; tile[row][tc4 + 1] = v.y;
    tile[row][tc4 + 2] = v.z; tile[row][tc4 + 3] = v.w;
  }
  __syncthreads();
#pragma unroll
  for (int p = 0; p < 4; ++p) {
    const int c = p * 16 + tr;
    us4 pk;
    pk.x = f2bf(tile[tc4 + 0][c]);
    pk.y = f2bf(tile[tc4 + 1][c]);
    pk.z = f2bf(tile[tc4 + 2][c]);
    pk.w = f2bf(tile[tc4 + 3][c]);
    *(us4*)&out[base + (long)(c0 + c) * D_ + r0 + tc4] = pk;
  }
}

// ---------------- Pass 0b: convert weights; A2 = [W3 | W4] 1024x2048
__global__ __launch_bounds__(256) void convert_weights(
    const float* __restrict__ Wp, const float* __restrict__ W3,
    const float* __restrict__ W4, unsigned short* __restrict__ Wpb,
    unsigned short* __restrict__ A2) {
  const int i = blockIdx.x * 256 + threadIdx.x;
  const long e = (long)i * 4;
  const int row = (int)(e >> 10);
  const int col = (int)(e & 1023);
  const float4 a = ((const float4*)Wp)[i];
  us4 pa; pa.x = f2bf(a.x); pa.y = f2bf(a.y); pa.z = f2bf(a.z); pa.w = f2bf(a.w);
  ((us4*)Wpb)[i] = pa;
  const float4 w3 = ((const float4*)W3)[i];
  us4 p3; p3.x = f2bf(w3.x); p3.y = f2bf(w3.y); p3.z = f2bf(w3.z); p3.w = f2bf(w3.w);
  *(us4*)&A2[(long)row * 2048 + col] = p3;
  const float4 w4 = ((const float4*)W4)[i];
  us4 p4; p4.x = f2bf(w4.x); p4.y = f2bf(w4.y); p4.z = f2bf(w4.z); p4.w = f2bf(w4.w);
  *(us4*)&A2[(long)row * 2048 + 1024 + col] = p4;
}

// ---------------- 256x256 phase-pipelined GEMM (both passes)
// A: [1024][LDA] bf16 row-major (k-contiguous). B^T rows: [1024][1024] k-major.
// gemm1 (!IS_G2): B^T = Qt[b]; out = qt (bf16 k-major) with +bias.
// gemm2 ( IS_G2): B^T rows kt<16 from Mt[b], kt>=16 from qt[b];
//                 out fp32 = relu(acc+bias) * q (read from qt k-major).
//
// Tile t lives in LDS buf t&1. Per tile (4 phases, ONE barrier each):
//   even t (quadrants m0nL, m0nH, m1nH, m1nL):
//     ph0: [rd bHi(p)]          MFMA aLo*bLo
//     ph1: [rd aHi(p); vmcnt0]  MFMA aLo*bHi      (vmcnt: t+1 data landed)
//     ph2: [rd aLo'(q)]         MFMA aHi*bHi
//     ph3: [rd bHi'(q); stage t+2 -> p]  MFMA aHi*bLo
//   odd t (quadrants m0nH, m0nL, m1nL, m1nH): symmetric with bLo<->bHi.
// Every lgkmcnt(0) waits exactly the batch issued one phase earlier.
template <int NT, int LDA, bool IS_G2>
__global__ __launch_bounds__(512, 2) void gemmpl(
    const unsigned short* __restrict__ A,
    const unsigned short* __restrict__ B1,
    const unsigned short* __restrict__ B2,
    const float* __restrict__ bias,
    void* __restrict__ outp) {
  __shared__ __align__(16) unsigned short As[2][256 * 64];
  __shared__ __align__(16) unsigned short Bs[2][256 * 64];

  const int lane = threadIdx.x & 63;
  const int w = threadIdx.x >> 6;
  const int wm = (w >> 2) * 128;   // wave M offset: rows wm..wm+127
  const int wn = (w & 3) * 64;     // wave N offset: rows wn..wn+63
  const int l15 = lane & 15;
  const int quad = lane >> 4;

  // T1: bijective chunked XCD swizzle (nwg=512, 512%8==0)
  const int bid = blockIdx.x;
  const int swz = (bid & 7) * 64 + (bid >> 3);
  const int b = swz >> 4;
  const int m0 = ((swz >> 2) & 3) * 256;
  const int n0 = (swz & 3) * 256;
  const long bb = ((long)b) << 20;

  // staging: linear LDS dest; global source pre-swizzled so the read-side
  // XOR (byte ^= (row&7)<<4) sees the right data (rule 21)
  const int sr = lane >> 3;
  const int sc = ((lane & 7) ^ sr) * 8;

  const unsigned short* Ag = A + (long)(m0 + w * 16 + sr) * LDA + sc;
  const unsigned short* Bg1 = B1 + bb + (long)(n0 + w * 16 + sr) * D_ + sc;
  const unsigned short* Bg2 =
      B2 ? (B2 + bb + (long)(n0 + w * 16 + sr) * D_ + sc) : (const unsigned short*)0;

  const int kx0 = (quad * 16) ^ ((lane & 7) << 4);
  const int kx1 = (64 + quad * 16) ^ ((lane & 7) << 4);

  floatx4 acc[8][4] = {};
  short8 aLo[4][2], aHi[4][2], bLo[2][2], bHi[2][2];

  // stage one operand tile (256x64) = 4 global_load_lds per wave; dest = kt&1
  auto stageA = [&](int kt) {
    unsigned short* dst = &As[kt & 1][0];
#pragma unroll
    for (int h = 0; h < 2; ++h)
#pragma unroll
      for (int j = 0; j < 2; ++j)
        async_load16(Ag + (long)(h * 128 + j * 8) * LDA + (long)kt * 64,
                     dst + (h * 128 + w * 16 + j * 8) * 64);
  };
  auto stageB = [&](int kt) {
    unsigned short* dst = &Bs[kt & 1][0];
    const unsigned short* bs;
    if constexpr (IS_G2) {
      bs = (kt < 16) ? (Bg1 + (long)kt * 64) : (Bg2 + (long)(kt - 16) * 64);
    } else {
      bs = Bg1 + (long)kt * 64;
    }
#pragma unroll
    for (int h = 0; h < 2; ++h)
#pragma unroll
      for (int j = 0; j < 2; ++j)
        async_load16(bs + (long)(h * 128 + j * 8) * D_,
                     dst + (h * 128 + w * 16 + j * 8) * 64);
  };

  auto ldA = [&](int buf, int fi, int kx) -> short8 {
    return *(const short8*)((const char*)&As[buf][0] +
                            (long)((wm + fi * 16 + l15) * 128 + kx));
  };
  auto ldB = [&](int buf, int fi, int kx) -> short8 {
    return *(const short8*)((const char*)&Bs[buf][0] +
                            (long)((wn + fi * 16 + l15) * 128 + kx));
  };

  auto rdALo = [&](int buf) {
#pragma unroll
    for (int r = 0; r < 4; ++r) { aLo[r][0] = ldA(buf, r, kx0); aLo[r][1] = ldA(buf, r, kx1); }
  };
  auto rdAHi = [&](int buf) {
#pragma unroll
    for (int r = 0; r < 4; ++r) { aHi[r][0] = ldA(buf, 4 + r, kx0); aHi[r][1] = ldA(buf, 4 + r, kx1); }
  };
  auto rdBLo = [&](int buf) {
#pragma unroll
    for (int c = 0; c < 2; ++c) { bLo[c][0] = ldB(buf, c, kx0); bLo[c][1] = ldB(buf, c, kx1); }
  };
  auto rdBHi = [&](int buf) {
#pragma unroll
    for (int c = 0; c < 2; ++c) { bHi[c][0] = ldB(buf, 2 + c, kx0); bHi[c][1] = ldB(buf, 2 + c, kx1); }
  };

  // prologue: tiles 0 and 1 staged; tile0 awaited; first read batch issued
  stageA(0); stageB(0);
  stageA(1); stageB(1);
  VMCNT8();
  BAR();
  rdALo(0); rdBLo(0);   // tile0.ph0 operands (12 ds_read)

  auto tileEven = [&](int t) {  // buf p=0, q=1
    // ph0: MFMA aLo*bLo  | issue bHi(t)
    BAR(); LGKM0(); SCHED0();
    rdBHi(0);
    SCHED0();
    MQ(aLo, bLo, 0, 0);
    // ph1: MFMA aLo*bHi  | issue aHi(t); vmcnt0 -> tile t+1 landed in buf1
    BAR(); LGKM0(); SCHED0();
    rdAHi(0);
    VMCNT0();
    SCHED0();
    MQ(aLo, bHi, 0, 2);
    // ph2: MFMA aHi*bHi  | issue aLo(t+1) from buf1
    BAR(); LGKM0(); SCHED0();
    if (t + 1 < NT) rdALo(1);
    SCHED0();
    MQ(aHi, bHi, 4, 2);
    // ph3: MFMA aHi*bLo  | issue bHi(t+1) from buf1; stage t+2 -> buf0
    BAR(); LGKM0(); SCHED0();
    if (t + 1 < NT) rdBHi(1);
    if (t + 2 < NT) { stageA(t + 2); stageB(t + 2); }
    SCHED0();
    MQ(aHi, bLo, 4, 0);
  };

  auto tileOdd = [&](int t) {  // buf p=1, q=0
    // ph0: MFMA aLo*bHi  | issue bLo(t)
    BAR(); LGKM0(); SCHED0();
    rdBLo(1);
    SCHED0();
    MQ(aLo, bHi, 0, 2);
    // ph1: MFMA aLo*bLo  | issue aHi(t); vmcnt0 -> tile t+1 landed in buf0
    BAR(); LGKM0(); SCHED0();
    rdAHi(1);
    VMCNT0();
    SCHED0();
    MQ(aLo, bLo, 0, 0);
    // ph2: MFMA aHi*bLo  | issue aLo(t+1) from buf0
    BAR(); LGKM0(); SCHED0();
    if (t + 1 < NT) rdALo(0);
    SCHED0();
    MQ(aHi, bLo, 4, 0);
    // ph3: MFMA aHi*bHi  | issue bLo(t+1) from buf0; stage t+2 -> buf1
    BAR(); LGKM0(); SCHED0();
    if (t + 1 < NT) rdBLo(0);
    if (t + 2 < NT) { stageA(t + 2); stageB(t + 2); }
    SCHED0();
    MQ(aHi, bHi, 4, 2);
  };

#pragma unroll 1
  for (int tt = 0; tt < NT; tt += 2) {
    tileEven(tt);
    tileOdd(tt + 1);
  }

  // ---- epilogue. C/D map: col = n-part + (lane&15), row = m-part + quad*4 + reg
  if constexpr (!IS_G2) {
    unsigned short* qt = (unsigned short*)outp;
#pragma unroll
    for (int c = 0; c < 4; ++c) {
      const int col = n0 + wn + c * 16 + l15;
      const float bv = bias[col];
#pragma unroll
      for (int r = 0; r < 8; ++r) {
        const int row = m0 + wm + r * 16 + quad * 4;
        const floatx4 v = acc[r][c];
        us4 pk;
        pk.x = f2bf(v.x + bv); pk.y = f2bf(v.y + bv);
        pk.z = f2bf(v.z + bv); pk.w = f2bf(v.w + bv);
        *(us4*)&qt[bb + (long)col * D_ + row] = pk;
      }
    }
  } else {
    float* outv = (float*)outp;
#pragma unroll
    for (int c = 0; c < 4; ++c) {
      const int col = n0 + wn + c * 16 + l15;
      const float bv = bias[col];
#pragma unroll
      for (int r = 0; r < 8; ++r) {
        const int row = m0 + wm + r * 16 + quad * 4;
        const floatx4 v = acc[r][c];
        const us4 qv = *(const us4*)&B2[bb + (long)col * D_ + row];
        outv[bb + (long)(row + 0) * D_ + col] = fmaxf(v.x + bv, 0.0f) * bf2f(qv.x);
        outv[bb + (long)(row + 1) * D_ + col] = fmaxf(v.y + bv, 0.0f) * bf2f(qv.y);
        outv[bb + (long)(row + 2) * D_ + col] = fmaxf(v.z + bv, 0.0f) * bf2f(qv.z);
        outv[bb + (long)(row + 3) * D_ + col] = fmaxf(v.w + bv, 0.0f) * bf2f(qv.w);
      }
    }
  }
}

extern "C" void kernel_launch(void* const* d_in, const int* in_sizes, int n_in,
                              void* d_out, int out_size, void* d_ws, size_t ws_size,
                              hipStream_t stream) {
  const float* Q  = (const float*)d_in[1];
  const float* M  = (const float*)d_in[2];
  const float* Wp = (const float*)d_in[4];
  const float* bp = (const float*)d_in[5];
  const float* W3 = (const float*)d_in[6];
  const float* W4 = (const float*)d_in[7];
  const float* b3 = (const float*)d_in[8];
  float* out = (float*)d_out;

  char* ws = (char*)d_ws;
  unsigned short* qt  = (unsigned short*)(ws);                 // 64 MiB: q^T bf16
  unsigned short* Qt  = (unsigned short*)(ws + (64l  << 20));  // 64 MiB: Q^T bf16
  unsigned short* Mt  = (unsigned short*)(ws + (128l << 20));  // 64 MiB: M^T bf16
  unsigned short* Wpb = (unsigned short*)(ws + (192l << 20));  // 2 MiB
  unsigned short* A2  = (unsigned short*)(ws + (194l << 20));  // 4 MiB: [W3|W4]

  dim3 tgrid(16, 16, 64);
  transpose_cvt2<<<tgrid, 256, 0, stream>>>(Q, Qt, M, Mt);
  convert_weights<<<1024, 256, 0, stream>>>(Wp, W3, W4, Wpb, A2);

  // gemm1: q^T = (Wp @ Q[b] + bp)^T   -> qt
  gemmpl<16, 1024, false><<<dim3(512), dim3(512), 0, stream>>>(
      Wpb, Qt, (const unsigned short*)nullptr, bp, qt);
  // gemm2: out = relu([W3|W4] @ [M;q] + b3) * q
  gemmpl<32, 2048, true><<<dim3(512), dim3(512), 0, stream>>>(
      A2, Mt, qt, b3, out);
}